// Round 1
// 394.171 us; speedup vs baseline: 1.0629x; 1.0629x over previous
//
#include <hip/hip_runtime.h>
#include <stdint.h>

// CrossAttention fused pipeline for MI355X (gfx950).
// R5: attention overhaul.
//  - Both cross-attentions merged into ONE dispatch (1536 blocks) so the two
//    independent jobs overlap; attn1 alone was only 2 blocks/CU.
//  - Swapped QK^T: mfma(K,Q) puts S for q-row=lane&15 in-lane; softmax P is
//    packed with v_cvt_pk_bf16_f32 (2 f32 -> 1 u32) and staged through LDS
//    with b64 writes / b128 reads (8+4 LDS ops/iter vs 32 scalar writes + 4
//    reads before; ~96 f2bf VALU ops/iter removed).
//  - LDS parity double-buffer kills cross-iteration WAR waits; 36-u32 row pad
//    is conflict-free at b64/b128 granularity.
//  - GEMM: __launch_bounds__(256,3) to shave 176->170 unified regs (3 blocks/CU).
// R4 GEMM structure otherwise kept (BK=64, XOR-swizzled LDS, XCD m-partition).

#define DIM 1024
#define HEADS 16
#define DK 64
#define BATCH 8
#define NTXT 512
#define NVIS 1024

typedef __attribute__((ext_vector_type(8))) short bf16x8;
typedef __attribute__((ext_vector_type(4))) float f32x4;
typedef __attribute__((ext_vector_type(4))) unsigned short u16x4;
typedef __attribute__((ext_vector_type(2))) unsigned int u32x2;
typedef __attribute__((ext_vector_type(4))) unsigned int u32x4;

__device__ inline unsigned short f2bf(float f) {
    unsigned u = __builtin_bit_cast(unsigned, f);
    u += 0x7fffu + ((u >> 16) & 1u);   // round-to-nearest-even
    return (unsigned short)(u >> 16);
}
__device__ inline f32x4 mfma16(bf16x8 a, bf16x8 b, f32x4 c) {
    return __builtin_amdgcn_mfma_f32_16x16x32_bf16(a, b, c, 0, 0, 0);
}
// async global->LDS, 16B per lane. LDS dest = wave-uniform base + lane*16.
__device__ inline void gl_lds16(const unsigned short* gp, unsigned short* lp) {
    const auto* g1 = reinterpret_cast<const __attribute__((address_space(1))) unsigned int*>(
        reinterpret_cast<uintptr_t>(gp));
    auto* l3 = reinterpret_cast<__attribute__((address_space(3))) unsigned int*>(
        reinterpret_cast<uintptr_t>(lp));
    __builtin_amdgcn_global_load_lds(g1, l3, 16, 0, 0);
}

// ---------------------------------------------------------------- weights cvt
struct WPtrs { const float* w[6]; };

__global__ __launch_bounds__(256) void cvt_w_kernel(WPtrs p, unsigned short* __restrict__ out) {
    int g = blockIdx.y;
    int i = blockIdx.x * 256 + threadIdx.x;          // groups of 4 floats
    float4 v = ((const float4*)p.w[g])[i];
    u16x4 o;
    o[0] = f2bf(v.x); o[1] = f2bf(v.y); o[2] = f2bf(v.z); o[3] = f2bf(v.w);
    *(u16x4*)(out + (size_t)g * (DIM * DIM) + (size_t)i * 4) = o;
}

// ------------------------------------------------------- layernorm + residual
__global__ __launch_bounds__(256) void ln_copy_kernel(
        const float* __restrict__ x, const float* __restrict__ g,
        const float* __restrict__ bta, unsigned short* __restrict__ xn,
        float* __restrict__ res) {
    int row = blockIdx.x;
    int tid = threadIdx.x;
    const float4* xr = (const float4*)(x + (size_t)row * DIM);
    float4 v = xr[tid];
    float s = v.x + v.y + v.z + v.w;
    float ss = v.x * v.x + v.y * v.y + v.z * v.z + v.w * v.w;
#pragma unroll
    for (int m = 1; m < 64; m <<= 1) { s += __shfl_xor(s, m); ss += __shfl_xor(ss, m); }
    __shared__ float red[8];
    int wave = tid >> 6, lane = tid & 63;
    if (lane == 0) { red[wave] = s; red[4 + wave] = ss; }
    __syncthreads();
    s = red[0] + red[1] + red[2] + red[3];
    ss = red[4] + red[5] + red[6] + red[7];
    float mu = s * (1.0f / DIM);
    float var = ss * (1.0f / DIM) - mu * mu;
    float rinv = rsqrtf(var + 1e-5f);
    float4 gv = ((const float4*)g)[tid];
    float4 bv = ((const float4*)bta)[tid];
    ((float4*)(res + (size_t)row * DIM))[tid] = v;    // residual passthrough
    u16x4 o;
    o[0] = f2bf((v.x - mu) * rinv * gv.x + bv.x);
    o[1] = f2bf((v.y - mu) * rinv * gv.y + bv.y);
    o[2] = f2bf((v.z - mu) * rinv * gv.z + bv.z);
    o[3] = f2bf((v.w - mu) * rinv * gv.w + bv.w);
    *(u16x4*)(xn + (size_t)row * DIM + tid * 4) = o;
}

// -------------------------------------------------------------- fused QKV GEMM
// C[m][n] = sum_k A[m][k] * W[n][k] + bias[n]   (NT layout)
// g in {2,5} (V projections) write TRANSPOSED: Vt[b][h][d][npos]
struct GemmParams {
    const unsigned short* A[2];      // [0]=t_norm (M=4096), [1]=v_norm (M=8192)
    const unsigned short* W;         // 6 contiguous bf16 weight matrices
    const float* bias[6];
    unsigned short* out[6];          // out[2],out[5] are transposed-V buffers
};

__global__ __launch_bounds__(256, 3) void gemm_qkv_kernel(GemmParams P) {
    int bid = blockIdx.x;
    int xcd = bid & 7;
    int idx = bid >> 3;                 // 0..287 per XCD
    int g, tm, tn;
    if (idx < 96) {                     // text: 24 columns x 4 m-tiles
        int col = idx >> 2, mi = idx & 3;
        g = col >> 3; tn = col & 7; tm = xcd * 4 + mi;
    } else {                            // vision: 24 columns x 8 m-tiles
        int j = idx - 96;
        int col = j >> 3, mi = j & 7;
        g = 3 + (col >> 3); tn = col & 7; tm = xcd * 8 + mi;
    }
    const unsigned short* A = P.A[g < 3 ? 0 : 1];
    const unsigned short* Ap = A + (size_t)tm * 128 * DIM;
    const unsigned short* Wp = P.W + (size_t)g * (DIM * DIM) + (size_t)tn * 128 * DIM;

    __shared__ __align__(16) unsigned short As[128][64];
    __shared__ __align__(16) unsigned short Bs[128][64];

    int tid = threadIdx.x;
    int wave = tid >> 6, lane = tid & 63;
    int wm = (wave & 1) * 64, wn = (wave >> 1) * 64;
    int col16 = lane & 15, quad = lane >> 4;

    // staging: 1024 16B-slots per buffer; slot s -> row=s>>3, pos=s&7;
    // global chunk fetched into pos p of row r is c = p ^ (r&7).
    int sbase = wave * 64 + lane;
    size_t ga[4];
    unsigned short* lA[4];
    unsigned short* lB[4];
#pragma unroll
    for (int i = 0; i < 4; i++) {
        int s = sbase + i * 256;
        int row = s >> 3;
        int c = (s & 7) ^ (row & 7);
        ga[i] = (size_t)row * DIM + (size_t)c * 8;
        lA[i] = &As[0][0] + (size_t)s * 8;
        lB[i] = &Bs[0][0] + (size_t)s * 8;
    }

    f32x4 zero = {0.f, 0.f, 0.f, 0.f};
    f32x4 acc[4][4];
#pragma unroll
    for (int i = 0; i < 4; i++)
#pragma unroll
        for (int j = 0; j < 4; j++) acc[i][j] = zero;

    for (int k0 = 0; k0 < DIM; k0 += 64) {
        __syncthreads();                                  // WAR on LDS
#pragma unroll
        for (int i = 0; i < 4; i++) {
            gl_lds16(Ap + ga[i] + k0, lA[i]);
            gl_lds16(Wp + ga[i] + k0, lB[i]);
        }
        __syncthreads();                                  // drain + RAW
#pragma unroll
        for (int ks = 0; ks < 2; ks++) {
            bf16x8 af[4], bfr[4];
#pragma unroll
            for (int mi = 0; mi < 4; mi++) {
                int r = wm + mi * 16 + col16;
                int p = (ks * 4 + quad) ^ (r & 7);
                af[mi] = *(const bf16x8*)&As[r][p * 8];
            }
#pragma unroll
            for (int ni = 0; ni < 4; ni++) {
                int r = wn + ni * 16 + col16;
                int p = (ks * 4 + quad) ^ (r & 7);
                bfr[ni] = *(const bf16x8*)&Bs[r][p * 8];
            }
#pragma unroll
            for (int mi = 0; mi < 4; mi++)
#pragma unroll
                for (int ni = 0; ni < 4; ni++)
                    acc[mi][ni] = mfma16(af[mi], bfr[ni], acc[mi][ni]);
        }
    }

    const float* bias = P.bias[g];
    unsigned short* out = P.out[g];
    float bv[4];
#pragma unroll
    for (int ni = 0; ni < 4; ni++) bv[ni] = bias[tn * 128 + wn + ni * 16 + col16];

    if (g == 2 || g == 5) {
        int N = (g == 2) ? NTXT : NVIS;
#pragma unroll
        for (int mi = 0; mi < 4; mi++) {
            int row0 = tm * 128 + wm + mi * 16 + quad * 4;
            int b = row0 / N;
            int npos = row0 - b * N;
#pragma unroll
            for (int ni = 0; ni < 4; ni++) {
                int col = tn * 128 + wn + ni * 16 + col16;
                int h = col >> 6, d = col & 63;
                u16x4 pk;
#pragma unroll
                for (int reg = 0; reg < 4; reg++) pk[reg] = f2bf(acc[mi][ni][reg] + bv[ni]);
                *(u16x4*)(out + ((size_t)((b * HEADS + h) * DK + d)) * N + npos) = pk;
            }
        }
    } else {
#pragma unroll
        for (int mi = 0; mi < 4; mi++) {
#pragma unroll
            for (int reg = 0; reg < 4; reg++) {
                int row = tm * 128 + wm + mi * 16 + quad * 4 + reg;
#pragma unroll
                for (int ni = 0; ni < 4; ni++) {
                    out[(size_t)row * DIM + tn * 128 + wn + ni * 16 + col16] =
                        f2bf(acc[mi][ni][reg] + bv[ni]);
                }
            }
        }
    }
}

// ------------------------------------------------------- flash cross-attention
// ONE dispatch for both directions: blocks [0,512) do text-q -> vision-KV,
// blocks [512,1536) do vision-q -> text-KV (jobs are independent; merging
// overlaps them and triples attn1's resident-wave pool).
// Swapped QK^T: c = mfma(K_frag, Q_frag) => lane (quad,c) holds
// S[q = mgbase + c][kv = nb + nt*16 + quad*4 + reg].  P is packed in-register
// (v_cvt_pk_bf16_f32) and staged via b64 LDS writes / b128 reads into the PV
// A-fragment layout P[q = c][kv = nb + h*32 + quad*8 + j].
// Row-sum: per-lane partials + 2 shfl_xor in the epilogue (no LDS, no branch).
__global__ __launch_bounds__(256) void attn_kernel(
        const unsigned short* __restrict__ Q1, const unsigned short* __restrict__ K1,
        const unsigned short* __restrict__ V1t, float* __restrict__ O1,
        const unsigned short* __restrict__ Q2, const unsigned short* __restrict__ K2,
        const unsigned short* __restrict__ V2t, float* __restrict__ O2) {
    int bid = blockIdx.x;
    const unsigned short* Q; const unsigned short* K; const unsigned short* Vt;
    float* Out; int Nq, Nkv;
    if (bid < 512) { Q = Q1; K = K1; Vt = V1t; Out = O1; Nq = NTXT; Nkv = NVIS; }
    else { bid -= 512; Q = Q2; K = K2; Vt = V2t; Out = O2; Nq = NVIS; Nkv = NTXT; }
    int bh = bid & 127;                 // 128 (b,h) pairs; xcd = bid&7 affinity kept
    int qt = bid >> 7;                  // q-tile of 128 rows
    int b = bh >> 4, h = bh & 15;
    int tid = threadIdx.x;
    int wave = tid >> 6, lane = tid & 63;
    int col16 = lane & 15, quad = lane >> 4;

    // [parity][wave][mg][qrow][u32]; 36-u32 row pad: b64 writes / b128 reads
    // land at the 4-accesses-per-bank minimum (no conflict serialization).
    __shared__ __align__(16) unsigned int Ps[2][4][2][16][36];

    const unsigned short* qbase =
        Q + ((size_t)(b * Nq + qt * 128 + wave * 32 + col16)) * DIM + h * DK;
    bf16x8 qa[2][2];
#pragma unroll
    for (int mg = 0; mg < 2; mg++) {
        qa[mg][0] = *(const bf16x8*)(qbase + (size_t)mg * 16 * DIM + quad * 8);
        qa[mg][1] = *(const bf16x8*)(qbase + (size_t)mg * 16 * DIM + 32 + quad * 8);
    }

    const unsigned short* Kbase = K + (size_t)b * Nkv * DIM + h * DK;
    const unsigned short* Vbase = Vt + (size_t)(b * HEADS + h) * DK * Nkv;

    f32x4 zero = {0.f, 0.f, 0.f, 0.f};
    f32x4 o[2][4];
#pragma unroll
    for (int mg = 0; mg < 2; mg++)
#pragma unroll
        for (int d = 0; d < 4; d++) o[mg][d] = zero;
    float lsum[2] = {0.f, 0.f};
    const float kexp = 0.18033688f;     // (1/8) * log2(e)

    int par = 0;
    for (int nb = 0; nb < Nkv; nb += 64, par ^= 1) {
        // V fragments early (B-operand for PV)
        bf16x8 vf[2][4];
#pragma unroll
        for (int half = 0; half < 2; half++)
#pragma unroll
            for (int d = 0; d < 4; d++)
                vf[half][d] = *(const bf16x8*)(
                    Vbase + (size_t)(d * 16 + col16) * Nkv + nb + half * 32 + quad * 8);

        unsigned int (*ps)[16][36] = Ps[par][wave];

        // QK^T (swapped) + softmax-numerator + pack + staged write
#pragma unroll
        for (int nt = 0; nt < 4; nt++) {
            const unsigned short* kp = Kbase + (size_t)(nb + nt * 16 + col16) * DIM;
            bf16x8 k0 = *(const bf16x8*)(kp + quad * 8);
            bf16x8 k1 = *(const bf16x8*)(kp + 32 + quad * 8);
#pragma unroll
            for (int mg = 0; mg < 2; mg++) {
                f32x4 c = zero;
                c = mfma16(k0, qa[mg][0], c);
                c = mfma16(k1, qa[mg][1], c);
                float p0 = exp2f(c[0] * kexp);
                float p1 = exp2f(c[1] * kexp);
                float p2 = exp2f(c[2] * kexp);
                float p3 = exp2f(c[3] * kexp);
                lsum[mg] += (p0 + p1) + (p2 + p3);
                unsigned int w01, w23;
                asm("v_cvt_pk_bf16_f32 %0, %1, %2" : "=v"(w01) : "v"(p0), "v"(p1));
                asm("v_cvt_pk_bf16_f32 %0, %1, %2" : "=v"(w23) : "v"(p2), "v"(p3));
                u32x2 pk2 = {w01, w23};
                *(u32x2*)&ps[mg][col16][nt * 8 + quad * 2] = pk2;
            }
        }

        // PV: A-frag = P[q=col16][kv chunk], B = V^T fragments
#pragma unroll
        for (int mg = 0; mg < 2; mg++) {
#pragma unroll
            for (int hh = 0; hh < 2; hh++) {
                u32x4 rw = *(const u32x4*)&ps[mg][col16][hh * 16 + quad * 4];
                bf16x8 pf = __builtin_bit_cast(bf16x8, rw);
#pragma unroll
                for (int d = 0; d < 4; d++) o[mg][d] = mfma16(pf, vf[hh][d], o[mg][d]);
            }
        }
    }

    // epilogue: denom for q-row col16 lives per-lane; butterfly over quads,
    // then pull denom[quad*4+reg] for the C-layout output rows.
#pragma unroll
    for (int mg = 0; mg < 2; mg++) {
        float l = lsum[mg];
        l += __shfl_xor(l, 16);
        l += __shfl_xor(l, 32);
#pragma unroll
        for (int reg = 0; reg < 4; reg++) {
            float inv = 1.0f / __shfl(l, quad * 4 + reg);
            int nrow = qt * 128 + wave * 32 + mg * 16 + quad * 4 + reg;
            float* op = Out + ((size_t)(b * Nq + nrow)) * DIM + h * DK;
#pragma unroll
            for (int d = 0; d < 4; d++) op[d * 16 + col16] = o[mg][d][reg] * inv;
        }
    }
}

// -------------------------------------------------------------------- launch
extern "C" void kernel_launch(void* const* d_in, const int* in_sizes, int n_in,
                              void* d_out, int out_size, void* d_ws, size_t ws_size,
                              hipStream_t stream) {
    const float* text   = (const float*)d_in[0];
    const float* vision = (const float*)d_in[1];
    const float* n1g = (const float*)d_in[2];
    const float* n1b = (const float*)d_in[3];
    const float* n2g = (const float*)d_in[4];
    const float* n2b = (const float*)d_in[5];
    const float* W[6];
    const float* bias[6];
    for (int i = 0; i < 6; i++) {
        W[i]    = (const float*)d_in[6 + 2 * i];
        bias[i] = (const float*)d_in[7 + 2 * i];
    }

    float* out = (float*)d_out;
    float* a1   = out;                 // (8,512,1024)
    float* a2   = out + 4194304;       // (8,1024,1024)
    float* tres = out + 12582912;      // (8,512,1024)
    float* vres = out + 16777216;      // (8,1024,1024)

    char* ws = (char*)d_ws;
    unsigned short* Wc  = (unsigned short*)(ws);              // 12.0 MB
    unsigned short* tno = (unsigned short*)(ws + 12582912);   //  8.0 MB
    unsigned short* vno = (unsigned short*)(ws + 20971520);   // 16.0 MB
    unsigned short* tq  = (unsigned short*)(ws + 37748736);
    unsigned short* tk  = (unsigned short*)(ws + 46137344);
    unsigned short* tvT = (unsigned short*)(ws + 54525952);   // transposed
    unsigned short* vq  = (unsigned short*)(ws + 62914560);
    unsigned short* vk  = (unsigned short*)(ws + 79691776);
    unsigned short* vvT = (unsigned short*)(ws + 96468992);   // transposed

    WPtrs wp;
    for (int i = 0; i < 6; i++) wp.w[i] = W[i];
    cvt_w_kernel<<<dim3(1024, 6), 256, 0, stream>>>(wp, Wc);
    ln_copy_kernel<<<4096, 256, 0, stream>>>(text, n1g, n1b, tno, tres);
    ln_copy_kernel<<<8192, 256, 0, stream>>>(vision, n2g, n2b, vno, vres);

    GemmParams gp;
    gp.A[0] = tno; gp.A[1] = vno; gp.W = Wc;
    for (int i = 0; i < 6; i++) gp.bias[i] = bias[i];
    gp.out[0] = tq; gp.out[1] = tk; gp.out[2] = tvT;
    gp.out[3] = vq; gp.out[4] = vk; gp.out[5] = vvT;
    gemm_qkv_kernel<<<2304, 256, 0, stream>>>(gp);

    // both cross-attentions in one dispatch (independent jobs, overlap them)
    attn_kernel<<<1536, 256, 0, stream>>>(tq, vk, vvT, a1, vq, tk, tvT, a2);
}